// Round 15
// baseline (209.267 us; speedup 1.0000x reference)
//
#include <hip/hip_runtime.h>
#include <stdint.h>

#define NB 8
#define NC 256
#define NE 128
#define NHW 4096

typedef __bf16 v8bf __attribute__((ext_vector_type(8)));
typedef float v4f __attribute__((ext_vector_type(4)));
typedef float v16f __attribute__((ext_vector_type(16)));
typedef unsigned int v4u __attribute__((ext_vector_type(4)));
typedef unsigned int v2u __attribute__((ext_vector_type(2)));

typedef unsigned int __attribute__((address_space(1))) uint_g;
typedef unsigned int __attribute__((address_space(3))) uint_l;

#if __has_builtin(__builtin_amdgcn_exp2f)
#define EXP2F(x) __builtin_amdgcn_exp2f(x)
#else
#define EXP2F(x) exp2f(x)
#endif

// LDS-only barrier: drains lgkmcnt but NOT vmcnt (global prefetch/DMA stays in flight)
#define BARRIER_LDS() asm volatile("s_waitcnt lgkmcnt(0)\n\ts_barrier" ::: "memory")
#define WAIT_VM0()    asm volatile("s_waitcnt vmcnt(0)" ::: "memory")

// async global->LDS DMA, 16B per lane: LDS dst = uniform base + lane*16
__device__ __forceinline__ void dma16(const unsigned short* g, unsigned short* l) {
    __builtin_amdgcn_global_load_lds((const uint_g*)g, (uint_l*)l, 16, 0, 0);
}

// fp32 -> bf16 round-to-nearest-even
__device__ __forceinline__ unsigned short f2bf(float x) {
    union { float f; unsigned int u; } v; v.f = x;
    unsigned int r = v.u + 0x7fffu + ((v.u >> 16) & 1u);
    return (unsigned short)(r >> 16);
}

// pack two fp32 -> bf16x2, round-half-up (P in (0,1], R4-verified accuracy)
__device__ __forceinline__ unsigned int pack_bf2_ru(float a, float b) {
    union { float f; unsigned int u; } va, vb; va.f = a; vb.f = b;
    return ((va.u + 0x8000u) >> 16) | ((vb.u + 0x8000u) & 0xffff0000u);
}

// ---------------- K0: cast weights. Wbf[e][c], e<128 = w_theta*(scale*log2e), e>=128 = w_phi
__global__ __launch_bounds__(256) void cast_w_kernel(const float* __restrict__ wt,
                                                     const float* __restrict__ wp,
                                                     unsigned short* __restrict__ Wbf) {
    int i = blockIdx.x * 256 + threadIdx.x;
    const float QS = 0.08838834764831845f * 1.4426950408889634f;
    float v = (i < 32768) ? wt[i] * QS : wp[i - 32768];
    Wbf[i] = f2bf(v);
}

// ---------------- K1: projection (+ fused V cast). K is stored PRE-SWIZZLED
// (16B unit u at position u ^ (row&15) within each row) so attn's LDS DMA copy
// is read conflict-free with the R5-verified fragment pattern. Q unswizzled.
// V in TILED layout Vt[b][u=hw/8][c] (R12, verified) so attn A-frag loads are
// coalesced.  Unit assembly: thread j + partner j^1 via one shfl_xor pair.
__global__ __launch_bounds__(256, 2) void proj_kernel(const float* __restrict__ l,
                                                      const unsigned short* __restrict__ Wbf,
                                                      unsigned short* __restrict__ Qbf,
                                                      unsigned short* __restrict__ Kbf,
                                                      unsigned short* __restrict__ Vbf) {
    __shared__ __align__(16) unsigned short A[64][264];
    __shared__ __align__(16) unsigned short Ost[2][32][136];
    const int tid = threadIdx.x;
    const int b = blockIdx.x & 7;
    const int qt = (blockIdx.x >> 3) << 6;
    const float* lb = l + ((size_t)b * NC * NHW + qt);

    for (int s = 0; s < 16; ++s) {
        int f = tid + s * 256;
        int c = f >> 4, j = f & 15;
        float4 v = *(const float4*)(lb + (size_t)c * NHW + j * 4);
        ushort4 o4;
        o4.x = f2bf(v.x); o4.y = f2bf(v.y); o4.z = f2bf(v.z); o4.w = f2bf(v.w);
        A[j * 4 + 0][c] = o4.x;
        A[j * 4 + 1][c] = o4.y;
        A[j * 4 + 2][c] = o4.z;
        A[j * 4 + 3][c] = o4.w;
        // V tiled write: unit u = qt/8 + (j>>1); partner thread j^1 has other half
        unsigned int d0 = (unsigned int)o4.x | ((unsigned int)o4.y << 16);
        unsigned int d1 = (unsigned int)o4.z | ((unsigned int)o4.w << 16);
        unsigned int p0 = (unsigned int)__shfl_xor((int)d0, 1);
        unsigned int p1 = (unsigned int)__shfl_xor((int)d1, 1);
        if ((j & 1) == 0) {
            *(v4u*)(Vbf + (size_t)b * 1048576 +
                    ((size_t)((qt >> 3) + (j >> 1)) * 256 + c) * 8) = (v4u){d0, d1, p0, p1};
        }
    }
    __syncthreads();

    const int w = tid >> 6, L = tid & 63;
    const int l15 = L & 15, q4 = L >> 4;
    const v4f vz = {0.f, 0.f, 0.f, 0.f};
    v4f acc[4][4];
    for (int mt = 0; mt < 4; ++mt)
        for (int nt = 0; nt < 4; ++nt) acc[mt][nt] = vz;

    for (int kf = 0; kf < 8; ++kf) {
        int kc = kf * 32 + q4 * 8;
        v8bf a[4], bb[4];
        for (int mt = 0; mt < 4; ++mt)
            a[mt] = *(const v8bf*)&A[mt * 16 + l15][kc];
        for (int nt = 0; nt < 4; ++nt)
            bb[nt] = *(const v8bf*)(Wbf + (w * 64 + nt * 16 + l15) * 256 + kc);
        for (int mt = 0; mt < 4; ++mt)
            for (int nt = 0; nt < 4; ++nt)
                acc[mt][nt] = __builtin_amdgcn_mfma_f32_16x16x32_bf16(a[mt], bb[nt], acc[mt][nt], 0, 0, 0);
    }

    const int side = w >> 1;
    const int ebase = (w & 1) * 64;
#pragma unroll
    for (int ph = 0; ph < 2; ++ph) {
        __syncthreads();
#pragma unroll
        for (int mh = 0; mh < 2; ++mh) {
            int mt = ph * 2 + mh;
#pragma unroll
            for (int nt = 0; nt < 4; ++nt)
#pragma unroll
                for (int r = 0; r < 4; ++r) {
                    int q32 = mh * 16 + q4 * 4 + r;
                    Ost[side][q32][ebase + nt * 16 + l15] = f2bf(acc[mt][nt][r]);
                }
        }
        __syncthreads();
#pragma unroll
        for (int s = 0; s < 4; ++s) {
            int idx = tid + s * 256;
            int sd = idx >> 9, rem = idx & 511;
            int r32 = rem >> 4, c8 = rem & 15;
            unsigned short* dst = sd ? Kbf : Qbf;
            int c8s = sd ? (c8 ^ (r32 & 15)) : c8;   // pre-swizzle K only
            *(uint4*)(dst + ((size_t)b * NHW + qt + ph * 32 + r32) * NE + c8s * 8) =
                *(const uint4*)&Ost[sd][r32][c8 * 8];
        }
    }
}

// ---------------- K2: flash attention, SPLIT-LOOP producer/consumer waves,
// R15 = R13 with the GRID BUG FIXED: q-tile 64 -> work = 8 batches x 64
// q-tiles = 512 blocks.  R13/R14 launched 1024 blocks; blocks 512-1023
// computed q64 up to 8128 and wrote past the output buffer -> HSA abort
// (R13 "container failed twice" + R14 core dump were this fault, not infra).
// R13 thesis: TWO INDEPENDENT BLOCKS PER CU.  R11 (chain interleave) and R12
// (V coalescing) were both null at 42% MfmaUtil -> the 58% matrix-idle is
// CORRELATED STALL TIME of a single barrier-locked block (2 waves/SIMD, same
// round cadence).  Fix: q-tile 64, 256-thr blocks (2P+2C), k-tile 64, LDS
// 49.4 KB -> 2 phase-independent blocks co-resident per CU.  Still 2
// waves/SIMD (full 256-reg budget, no R1 spill) but from DIFFERENT blocks:
// when A stalls (barrier, vmcnt, ds latency), B issues.
// Reused verified pieces: R9 k64 DMA schedule + parities (P writes Pu[it&1],
// C reads Pu[(it-1)&1]; QK(i+1) reads Ku[(i+1)&1], DMA(i+2) fills Ku[i&1]),
// R5 swizzled QK reads, R9 scatter image, R11 interleave, R12 Vt layout.
// Barrier audit: both regions 2 prologue + 65 loop + 1 epilogue = 68.
// P waves w=0,1 own q-rows w*32..; C waves ci=w-2 own c-rows ci*128..
// (o[4][2]=128 regs + av[4][4]=64 -> C ~215 < 256).
// LDS: Ku dbuf 32K | Pu dbuf 16K | lsum 256B = 49408 B.
__global__ __launch_bounds__(256, 2) void attn_kernel(const unsigned short* __restrict__ Qbf,
                                                      const unsigned short* __restrict__ Kbf,
                                                      const unsigned short* __restrict__ Vbf,
                                                      float* __restrict__ out) {
    __shared__ __align__(16) unsigned char smem[49408];
    unsigned short* KuS = (unsigned short*)smem;             // 2 x 16KB, swizzled K tiles
    unsigned short* PuS = (unsigned short*)(smem + 32768);   // 2 x 8 frag-tiles x 1KB
    float* lsumF = (float*)(smem + 49152);                   // [2][32]

    const int tid = threadIdx.x;
    const int b = blockIdx.x & 7;                            // batch -> XCD affinity
    const int q64 = (blockIdx.x >> 3) << 6;                  // bid < 512 -> q64 <= 4032
    const int w = tid >> 6;                                  // wave 0-3 -> SIMD w
    const int L = tid & 63;
    const int l31 = L & 31, hi = L >> 5;
    const int x15 = l31 & 15;

    const unsigned short* Kb = Kbf + (size_t)b * NHW * NE;
    const unsigned short* Vt = Vbf + (size_t)b * 1048576;    // [u=k/8][c] 16B units

    if (w < 2) {
        // ==================== PRODUCER region (waves 0-1) ====================
        float lacc = 0.f;
        v8bf bq[8];
        const unsigned short* qrow = Qbf + ((size_t)b * NHW + q64 + w * 32 + l31) * NE + hi * 8;
#pragma unroll
        for (int ef = 0; ef < 8; ++ef)
            bq[ef] = *(const v8bf*)(qrow + ef * 16);
        // prologue A: DMA K tile 0 (64 rows = 16 chunks, 8/wave) -> buf 0
#pragma unroll
        for (int jj = 0; jj < 8; ++jj) {
            int j = w * 8 + jj;
            dma16(Kb + (size_t)j * 512 + L * 8, KuS + j * 512);
        }
        WAIT_VM0();
        BARRIER_LDS();                                       // barrier #1
        // prologue B: DMA K tile 1 -> buf 1; QK(0) -> s_prev (4-chain interleave)
#pragma unroll
        for (int jj = 0; jj < 8; ++jj) {
            int j = w * 8 + jj;
            dma16(Kb + (size_t)8192 + j * 512 + L * 8, KuS + 8192 + j * 512);
        }
        v16f s_prev[2];
        {
            v16f tmp[2];
#pragma unroll
            for (int kt = 0; kt < 2; ++kt)
#pragma unroll
                for (int r = 0; r < 16; ++r) { s_prev[kt][r] = 0.f; tmp[kt][r] = 0.f; }
#pragma unroll
            for (int ef = 0; ef < 4; ++ef)
#pragma unroll
                for (int kt = 0; kt < 2; ++kt) {
                    const unsigned short* krow = KuS + (kt * 32 + l31) * 128;
                    v8bf ak0 = *(const v8bf*)(krow + (((2 * ef + hi) ^ x15) * 8));
                    v8bf ak1 = *(const v8bf*)(krow + (((2 * (ef + 4) + hi) ^ x15) * 8));
                    s_prev[kt] = __builtin_amdgcn_mfma_f32_32x32x16_bf16(ak0, bq[ef], s_prev[kt], 0, 0, 0);
                    tmp[kt]    = __builtin_amdgcn_mfma_f32_32x32x16_bf16(ak1, bq[ef + 4], tmp[kt], 0, 0, 0);
                }
#pragma unroll
            for (int kt = 0; kt < 2; ++kt)
#pragma unroll
                for (int r = 0; r < 16; ++r) s_prev[kt][r] += tmp[kt][r];
        }
        WAIT_VM0();                                          // DMA(1) landed
        BARRIER_LDS();                                       // barrier #2

        // scatter-write address components (loop-invariant; R9-verified image)
        const int a1 = l31 * 8 + hi * 4;                     // shorts: unit l31, word-half hi
        const int a2 = (l31 + 32) * 8 + hi * 4;              // shorts: unit l31+32, word-half hi

        for (int it = 0; it < 65; ++it) {
            if (it < 64) {
                const int buf = it & 1;                      // Pu publish buf; DMA(i+2) Ku buf
                if (it <= 61) {
                    // DMA K(i+2) into Ku buf[(i+2)&1] = buf[i&1] (tile i dead: QK'd last iter)
                    const size_t kro = (size_t)(it + 2) * 8192;    // shorts: tile*64rows*128
#pragma unroll
                    for (int jj = 0; jj < 8; ++jj) {
                        int j = w * 8 + jj;
                        dma16(Kb + kro + j * 512 + L * 8, KuS + buf * 8192 + j * 512);
                    }
                }
                // softmax(i) from s_prev -> scatter into Pu[buf]
#pragma unroll
                for (int kt = 0; kt < 2; ++kt) {
                    float p[16];
#pragma unroll
                    for (int r = 0; r < 16; ++r) p[r] = EXP2F(s_prev[kt][r]);
                    {   // row-sum: depth-4 tree (R9-verified)
                        float t0 = (p[0] + p[1]) + (p[2] + p[3]);
                        float t1 = (p[4] + p[5]) + (p[6] + p[7]);
                        float t2 = (p[8] + p[9]) + (p[10] + p[11]);
                        float t3 = (p[12] + p[13]) + (p[14] + p[15]);
                        lacc += (t0 + t1) + (t2 + t3);
                    }
                    unsigned int pk[8];
#pragma unroll
                    for (int t = 0; t < 8; ++t) pk[t] = pack_bf2_ru(p[2 * t], p[2 * t + 1]);
                    unsigned short* base0 = PuS + buf * 4096 + (w * 4 + kt * 2) * 512;
                    *(v2u*)(base0 + a1)       = (v2u){pk[0], pk[1]};
                    *(v2u*)(base0 + a2)       = (v2u){pk[2], pk[3]};
                    *(v2u*)(base0 + 512 + a1) = (v2u){pk[4], pk[5]};
                    *(v2u*)(base0 + 512 + a2) = (v2u){pk[6], pk[7]};
                }
                // QK(i+1) -> s_prev (direct accumulate; 4 chains in flight)
                if (it <= 62) {
                    const unsigned short* kub = KuS + ((it + 1) & 1) * 8192;
                    v16f tmp[2];
#pragma unroll
                    for (int kt = 0; kt < 2; ++kt)
#pragma unroll
                        for (int r = 0; r < 16; ++r) { s_prev[kt][r] = 0.f; tmp[kt][r] = 0.f; }
#pragma unroll
                    for (int ef = 0; ef < 4; ++ef)
#pragma unroll
                        for (int kt = 0; kt < 2; ++kt) {
                            const unsigned short* krow = kub + (kt * 32 + l31) * 128;
                            v8bf ak0 = *(const v8bf*)(krow + (((2 * ef + hi) ^ x15) * 8));
                            v8bf ak1 = *(const v8bf*)(krow + (((2 * (ef + 4) + hi) ^ x15) * 8));
                            s_prev[kt] = __builtin_amdgcn_mfma_f32_32x32x16_bf16(ak0, bq[ef], s_prev[kt], 0, 0, 0);
                            tmp[kt]    = __builtin_amdgcn_mfma_f32_32x32x16_bf16(ak1, bq[ef + 4], tmp[kt], 0, 0, 0);
                        }
#pragma unroll
                    for (int kt = 0; kt < 2; ++kt)
#pragma unroll
                        for (int r = 0; r < 16; ++r) s_prev[kt][r] += tmp[kt][r];
                }
                WAIT_VM0();                                  // DMA(i+2) landed before barrier
            }
            BARRIER_LDS();                                   // barriers #3..#67
        }
        // epilogue: row-sum handoff
        float tot = lacc + __shfl_xor(lacc, 32);
        if (hi == 0) lsumF[w * 32 + l31] = tot;
        BARRIER_LDS();                                       // barrier #68
    } else {
        // ==================== CONSUMER region (waves 2-3) ====================
        const int ci = w - 2;
        v16f o[4][2];                                        // acc [ct][qt], 128 regs
#pragma unroll
        for (int ct = 0; ct < 4; ++ct)
#pragma unroll
            for (int qt = 0; qt < 2; ++qt)
#pragma unroll
                for (int r = 0; r < 16; ++r) o[ct][qt][r] = 0.f;
        // Vt addressing: av[ct][kf] = Vt[(u = tile*8 + kf*2 + hi)][c = ci*128 + ct*32 + l31]
        int crow[4];
#pragma unroll
        for (int ct = 0; ct < 4; ++ct) crow[ct] = ci * 128 + ct * 32 + l31;
        v8bf av[4][4];                                       // V frags of next PV tile
#pragma unroll
        for (int ct = 0; ct < 4; ++ct)
#pragma unroll
            for (int kf = 0; kf < 4; ++kf)
                av[ct][kf] = *(const v8bf*)(Vt + ((size_t)((kf * 2 + hi) * 256) + crow[ct]) * 8);
        BARRIER_LDS();                                       // barrier #1
        BARRIER_LDS();                                       // barrier #2 (P prologue B window)

        for (int it = 0; it < 65; ++it) {
            if (it > 0) {
                // PV over tile it-1 from Pu[(it-1)&1]; kf-major, 8 acc chains
                const int pbuf = (it - 1) & 1;
                const unsigned short* pb = PuS + pbuf * 4096 + (hi * 32 + l31) * 8;
#pragma unroll
                for (int kf = 0; kf < 4; ++kf) {
                    v8bf bp[2];
#pragma unroll
                    for (int qt = 0; qt < 2; ++qt)
                        bp[qt] = *(const v8bf*)(pb + (qt * 4 + kf) * 512);
#pragma unroll
                    for (int ct = 0; ct < 4; ++ct)
#pragma unroll
                        for (int qt = 0; qt < 2; ++qt)
                            o[ct][qt] = __builtin_amdgcn_mfma_f32_32x32x16_bf16(av[ct][kf], bp[qt], o[ct][qt], 0, 0, 0);
                }
                // reload V frags for tile it (wrapped at it=64: dead uniform load)
                const size_t uB = (size_t)(it & 63) * 8;
#pragma unroll
                for (int ct = 0; ct < 4; ++ct)
#pragma unroll
                    for (int kf = 0; kf < 4; ++kf)
                        av[ct][kf] = *(const v8bf*)(Vt + ((uB + kf * 2 + hi) * 256 + crow[ct]) * 8);
            }
            BARRIER_LDS();                                   // barriers #3..#67
        }
        BARRIER_LDS();                                       // barrier #68 (lsum ready)
        float inv[2];
#pragma unroll
        for (int qt = 0; qt < 2; ++qt) inv[qt] = 1.0f / lsumF[qt * 32 + l31];
        // store: O^T C/D lane = q-col -> coalesced dwords
#pragma unroll
        for (int ct = 0; ct < 4; ++ct)
#pragma unroll
            for (int qt = 0; qt < 2; ++qt) {
                float* ob = out + (size_t)b * NC * NHW + q64 + qt * 32 + l31;
#pragma unroll
                for (int r = 0; r < 16; ++r) {
                    int c = ci * 128 + ct * 32 + (r & 3) + 8 * (r >> 2) + 4 * hi;
                    ob[(size_t)c * NHW] = o[ct][qt][r] * inv[qt];
                }
            }
    }
}

extern "C" void kernel_launch(void* const* d_in, const int* in_sizes, int n_in,
                              void* d_out, int out_size, void* d_ws, size_t ws_size,
                              hipStream_t stream) {
    const float* l  = (const float*)d_in[0];
    const float* wt = (const float*)d_in[1];
    const float* wp = (const float*)d_in[2];
    float* out = (float*)d_out;

    char* ws = (char*)d_ws;
    unsigned short* Wbf = (unsigned short*)ws;                          // 131072 B
    unsigned short* Qbf = (unsigned short*)(ws + 131072);               // 8 MB
    unsigned short* Kbf = (unsigned short*)(ws + 131072 + 8388608);     // 8 MB (pre-swizzled)
    unsigned short* Vbf = (unsigned short*)(ws + 131072 + 16777216);    // 16 MB (tiled Vt[u][c])

    hipLaunchKernelGGL(cast_w_kernel, dim3(256), dim3(256), 0, stream, wt, wp, Wbf);
    hipLaunchKernelGGL(proj_kernel,   dim3(512), dim3(256), 0, stream, l, Wbf, Qbf, Kbf, Vbf);
    // q-tile 64: 8 batches x 64 q-tiles = 512 blocks (R13/R14 launched 1024 -> OOB fault)
    hipLaunchKernelGGL(attn_kernel,   dim3(512), dim3(256), 0, stream, Qbf, Kbf, Vbf, out);
}

// Round 16
// 202.483 us; speedup vs baseline: 1.0335x; 1.0335x over previous
//
#include <hip/hip_runtime.h>
#include <stdint.h>

#define NB 8
#define NC 256
#define NE 128
#define NHW 4096

typedef __bf16 v8bf __attribute__((ext_vector_type(8)));
typedef float v4f __attribute__((ext_vector_type(4)));
typedef float v16f __attribute__((ext_vector_type(16)));
typedef unsigned int v4u __attribute__((ext_vector_type(4)));
typedef unsigned int v2u __attribute__((ext_vector_type(2)));

typedef unsigned int __attribute__((address_space(1))) uint_g;
typedef unsigned int __attribute__((address_space(3))) uint_l;

#if __has_builtin(__builtin_amdgcn_exp2f)
#define EXP2F(x) __builtin_amdgcn_exp2f(x)
#else
#define EXP2F(x) exp2f(x)
#endif

// LDS-only barrier: drains lgkmcnt but NOT vmcnt (global prefetch/DMA stays in flight)
#define BARRIER_LDS() asm volatile("s_waitcnt lgkmcnt(0)\n\ts_barrier" ::: "memory")
#define WAIT_VM0()    asm volatile("s_waitcnt vmcnt(0)" ::: "memory")

// async global->LDS DMA, 16B per lane: LDS dst = uniform base + lane*16
__device__ __forceinline__ void dma16(const unsigned short* g, unsigned short* l) {
    __builtin_amdgcn_global_load_lds((const uint_g*)g, (uint_l*)l, 16, 0, 0);
}

// fp32 -> bf16 round-to-nearest-even
__device__ __forceinline__ unsigned short f2bf(float x) {
    union { float f; unsigned int u; } v; v.f = x;
    unsigned int r = v.u + 0x7fffu + ((v.u >> 16) & 1u);
    return (unsigned short)(r >> 16);
}

// pack two fp32 -> bf16x2, round-half-up (P in (0,1], R4-verified accuracy)
__device__ __forceinline__ unsigned int pack_bf2_ru(float a, float b) {
    union { float f; unsigned int u; } va, vb; va.f = a; vb.f = b;
    return ((va.u + 0x8000u) >> 16) | ((vb.u + 0x8000u) & 0xffff0000u);
}

// ---------------- K0: cast weights. Wbf[e][c], e<128 = w_theta*(scale*log2e), e>=128 = w_phi
__global__ __launch_bounds__(256) void cast_w_kernel(const float* __restrict__ wt,
                                                     const float* __restrict__ wp,
                                                     unsigned short* __restrict__ Wbf) {
    int i = blockIdx.x * 256 + threadIdx.x;
    const float QS = 0.08838834764831845f * 1.4426950408889634f;
    float v = (i < 32768) ? wt[i] * QS : wp[i - 32768];
    Wbf[i] = f2bf(v);
}

// ---------------- K1: projection (+ fused V cast). K is stored PRE-SWIZZLED
// (16B unit u at position u ^ (row&15) within each row) so attn's LDS DMA copy
// is read conflict-free with the R5-verified fragment pattern. Q unswizzled.
// V LINEAR layout (R12's tiled V was null for attn, cost ~3us here; reverted).
// R0-exact form (R6's 32-tile variant regressed: W re-read doubling).
__global__ __launch_bounds__(256, 2) void proj_kernel(const float* __restrict__ l,
                                                      const unsigned short* __restrict__ Wbf,
                                                      unsigned short* __restrict__ Qbf,
                                                      unsigned short* __restrict__ Kbf,
                                                      unsigned short* __restrict__ Vbf) {
    __shared__ __align__(16) unsigned short A[64][264];
    __shared__ __align__(16) unsigned short Ost[2][32][136];
    const int tid = threadIdx.x;
    const int b = blockIdx.x & 7;
    const int qt = (blockIdx.x >> 3) << 6;
    const float* lb = l + ((size_t)b * NC * NHW + qt);

    for (int s = 0; s < 16; ++s) {
        int f = tid + s * 256;
        int c = f >> 4, j = f & 15;
        float4 v = *(const float4*)(lb + (size_t)c * NHW + j * 4);
        ushort4 o4;
        o4.x = f2bf(v.x); o4.y = f2bf(v.y); o4.z = f2bf(v.z); o4.w = f2bf(v.w);
        A[j * 4 + 0][c] = o4.x;
        A[j * 4 + 1][c] = o4.y;
        A[j * 4 + 2][c] = o4.z;
        A[j * 4 + 3][c] = o4.w;
        *(ushort4*)(Vbf + (size_t)b * NC * NHW + (size_t)c * NHW + qt + j * 4) = o4;
    }
    __syncthreads();

    const int w = tid >> 6, L = tid & 63;
    const int l15 = L & 15, q4 = L >> 4;
    const v4f vz = {0.f, 0.f, 0.f, 0.f};
    v4f acc[4][4];
    for (int mt = 0; mt < 4; ++mt)
        for (int nt = 0; nt < 4; ++nt) acc[mt][nt] = vz;

    for (int kf = 0; kf < 8; ++kf) {
        int kc = kf * 32 + q4 * 8;
        v8bf a[4], bb[4];
        for (int mt = 0; mt < 4; ++mt)
            a[mt] = *(const v8bf*)&A[mt * 16 + l15][kc];
        for (int nt = 0; nt < 4; ++nt)
            bb[nt] = *(const v8bf*)(Wbf + (w * 64 + nt * 16 + l15) * 256 + kc);
        for (int mt = 0; mt < 4; ++mt)
            for (int nt = 0; nt < 4; ++nt)
                acc[mt][nt] = __builtin_amdgcn_mfma_f32_16x16x32_bf16(a[mt], bb[nt], acc[mt][nt], 0, 0, 0);
    }

    const int side = w >> 1;
    const int ebase = (w & 1) * 64;
#pragma unroll
    for (int ph = 0; ph < 2; ++ph) {
        __syncthreads();
#pragma unroll
        for (int mh = 0; mh < 2; ++mh) {
            int mt = ph * 2 + mh;
#pragma unroll
            for (int nt = 0; nt < 4; ++nt)
#pragma unroll
                for (int r = 0; r < 4; ++r) {
                    int q32 = mh * 16 + q4 * 4 + r;
                    Ost[side][q32][ebase + nt * 16 + l15] = f2bf(acc[mt][nt][r]);
                }
        }
        __syncthreads();
#pragma unroll
        for (int s = 0; s < 4; ++s) {
            int idx = tid + s * 256;
            int sd = idx >> 9, rem = idx & 511;
            int r32 = rem >> 4, c8 = rem & 15;
            unsigned short* dst = sd ? Kbf : Qbf;
            int c8s = sd ? (c8 ^ (r32 & 15)) : c8;   // pre-swizzle K only
            *(uint4*)(dst + ((size_t)b * NHW + qt + ph * 32 + r32) * NE + c8s * 8) =
                *(const uint4*)&Ost[sd][r32][c8 * 8];
        }
    }
}

// ---------------- K2: flash attention, SPLIT-LOOP P/C waves, R16: 12-WAVE
// BLOCK = 3 WAVES/SIMD WITH PAIRING PRESERVED.  Matrix of measured configs:
// 2 waves/SIMD paired = 109us (R12); 4 waves @128regs = spill (R1); 2 waves
// same-role = 129us (R15 -- 4-wave blocks put both P on SIMDs 0-1, both C on
// 2-3, destroying the pairing).  Untested cell: 3/SIMD paired.  12 waves:
// P w=0-3 -> SIMDs 0-3 (1 P each), C w=4-11 -> SIMDs 0-3 (2 C each).  Each C
// owns 32 c-rows -> o[4]=64 regs, C~110; P~150; __launch_bounds__(768,3) =
// 170-reg budget fits both, and 170-reg waves cap residency at 3/SIMD =
// exactly 1 block/CU.  q-tile 128, k-tile 64 (R9's verified schedule: P
// writes Pu[it&1], C reads Pu[(it-1)&1]; QK(i+1) reads Ku[(i+1)&1], DMA(i+2)
// fills Ku[i&1]).  R9 scatter image, R11 ef-major chains, linear V.
// Barrier audit: both regions 2 prologue + 65 loop + 1 epilogue = 68.
// Per SIMD per round: 1P(16) + 2C(16 each) = 48 MFMA = 1536 cyc demand; the
// 3rd wave exists to fill the ds-latency/exp2/drain bubbles that left 58%
// matrix-idle at 2 waves/SIMD (R10-R12 nulls).
// LDS: Ku dbuf 32K | Pu dbuf 32K | lsum 512B = 66048 B.
__global__ __launch_bounds__(768, 3) void attn_kernel(const unsigned short* __restrict__ Qbf,
                                                      const unsigned short* __restrict__ Kbf,
                                                      const unsigned short* __restrict__ Vbf,
                                                      float* __restrict__ out) {
    __shared__ __align__(16) unsigned char smem[66048];
    unsigned short* KuS = (unsigned short*)smem;             // 2 x 16KB, swizzled K tiles
    unsigned short* PuS = (unsigned short*)(smem + 32768);   // 2 x 16 frag-tiles x 1KB
    float* lsumF = (float*)(smem + 65536);                   // [4][32]

    const int tid = threadIdx.x;
    const int b = blockIdx.x & 7;                            // batch -> XCD affinity
    const int q128 = (blockIdx.x >> 3) << 7;                 // bid < 256 -> q128 <= 3968
    const int w = tid >> 6;                                  // wave 0-11 -> SIMD w&3
    const int L = tid & 63;
    const int l31 = L & 31, hi = L >> 5;
    const int x15 = l31 & 15;

    const unsigned short* Kb = Kbf + (size_t)b * NHW * NE;
    const unsigned short* Vb = Vbf + (size_t)b * NC * NHW;

    if (w < 4) {
        // ==================== PRODUCER region (waves 0-3, 1/SIMD) ====================
        float lacc = 0.f;
        v8bf bq[8];
        const unsigned short* qrow = Qbf + ((size_t)b * NHW + q128 + w * 32 + l31) * NE + hi * 8;
#pragma unroll
        for (int ef = 0; ef < 8; ++ef)
            bq[ef] = *(const v8bf*)(qrow + ef * 16);
        // prologue A: DMA K tile 0 (64 rows = 16 chunks, 4/wave) -> buf 0
#pragma unroll
        for (int jj = 0; jj < 4; ++jj) {
            int j = w * 4 + jj;
            dma16(Kb + (size_t)j * 512 + L * 8, KuS + j * 512);
        }
        WAIT_VM0();
        BARRIER_LDS();                                       // barrier #1
        // prologue B: DMA K tile 1 -> buf 1; QK(0) -> s_prev (4-chain interleave)
#pragma unroll
        for (int jj = 0; jj < 4; ++jj) {
            int j = w * 4 + jj;
            dma16(Kb + (size_t)8192 + j * 512 + L * 8, KuS + 8192 + j * 512);
        }
        v16f s_prev[2];
        {
            v16f tmp[2];
#pragma unroll
            for (int kt = 0; kt < 2; ++kt)
#pragma unroll
                for (int r = 0; r < 16; ++r) { s_prev[kt][r] = 0.f; tmp[kt][r] = 0.f; }
#pragma unroll
            for (int ef = 0; ef < 4; ++ef)
#pragma unroll
                for (int kt = 0; kt < 2; ++kt) {
                    const unsigned short* krow = KuS + (kt * 32 + l31) * 128;
                    v8bf ak0 = *(const v8bf*)(krow + (((2 * ef + hi) ^ x15) * 8));
                    v8bf ak1 = *(const v8bf*)(krow + (((2 * (ef + 4) + hi) ^ x15) * 8));
                    s_prev[kt] = __builtin_amdgcn_mfma_f32_32x32x16_bf16(ak0, bq[ef], s_prev[kt], 0, 0, 0);
                    tmp[kt]    = __builtin_amdgcn_mfma_f32_32x32x16_bf16(ak1, bq[ef + 4], tmp[kt], 0, 0, 0);
                }
#pragma unroll
            for (int kt = 0; kt < 2; ++kt)
#pragma unroll
                for (int r = 0; r < 16; ++r) s_prev[kt][r] += tmp[kt][r];
        }
        WAIT_VM0();                                          // DMA(1) landed
        BARRIER_LDS();                                       // barrier #2

        // scatter-write address components (loop-invariant; R9-verified image)
        const int a1 = l31 * 8 + hi * 4;                     // shorts: unit l31, word-half hi
        const int a2 = (l31 + 32) * 8 + hi * 4;              // shorts: unit l31+32, word-half hi

        for (int it = 0; it < 65; ++it) {
            if (it < 64) {
                const int buf = it & 1;                      // Pu publish buf; DMA(i+2) Ku buf
                if (it <= 61) {
                    // DMA K(i+2) into Ku buf[(i+2)&1] = buf[i&1] (tile i dead: QK'd last iter)
                    const size_t kro = (size_t)(it + 2) * 8192;    // shorts: tile*64rows*128
#pragma unroll
                    for (int jj = 0; jj < 4; ++jj) {
                        int j = w * 4 + jj;
                        dma16(Kb + kro + j * 512 + L * 8, KuS + buf * 8192 + j * 512);
                    }
                }
                // softmax(i) from s_prev -> scatter into Pu[buf]
#pragma unroll
                for (int kt = 0; kt < 2; ++kt) {
                    float p[16];
#pragma unroll
                    for (int r = 0; r < 16; ++r) p[r] = EXP2F(s_prev[kt][r]);
                    {   // row-sum: depth-4 tree (R9-verified)
                        float t0 = (p[0] + p[1]) + (p[2] + p[3]);
                        float t1 = (p[4] + p[5]) + (p[6] + p[7]);
                        float t2 = (p[8] + p[9]) + (p[10] + p[11]);
                        float t3 = (p[12] + p[13]) + (p[14] + p[15]);
                        lacc += (t0 + t1) + (t2 + t3);
                    }
                    unsigned int pk[8];
#pragma unroll
                    for (int t = 0; t < 8; ++t) pk[t] = pack_bf2_ru(p[2 * t], p[2 * t + 1]);
                    unsigned short* base0 = PuS + buf * 8192 + (w * 4 + kt * 2) * 512;
                    *(v2u*)(base0 + a1)       = (v2u){pk[0], pk[1]};
                    *(v2u*)(base0 + a2)       = (v2u){pk[2], pk[3]};
                    *(v2u*)(base0 + 512 + a1) = (v2u){pk[4], pk[5]};
                    *(v2u*)(base0 + 512 + a2) = (v2u){pk[6], pk[7]};
                }
                // QK(i+1) -> s_prev (direct accumulate; 4 chains in flight)
                if (it <= 62) {
                    const unsigned short* kub = KuS + ((it + 1) & 1) * 8192;
                    v16f tmp[2];
#pragma unroll
                    for (int kt = 0; kt < 2; ++kt)
#pragma unroll
                        for (int r = 0; r < 16; ++r) { s_prev[kt][r] = 0.f; tmp[kt][r] = 0.f; }
#pragma unroll
                    for (int ef = 0; ef < 4; ++ef)
#pragma unroll
                        for (int kt = 0; kt < 2; ++kt) {
                            const unsigned short* krow = kub + (kt * 32 + l31) * 128;
                            v8bf ak0 = *(const v8bf*)(krow + (((2 * ef + hi) ^ x15) * 8));
                            v8bf ak1 = *(const v8bf*)(krow + (((2 * (ef + 4) + hi) ^ x15) * 8));
                            s_prev[kt] = __builtin_amdgcn_mfma_f32_32x32x16_bf16(ak0, bq[ef], s_prev[kt], 0, 0, 0);
                            tmp[kt]    = __builtin_amdgcn_mfma_f32_32x32x16_bf16(ak1, bq[ef + 4], tmp[kt], 0, 0, 0);
                        }
#pragma unroll
                    for (int kt = 0; kt < 2; ++kt)
#pragma unroll
                        for (int r = 0; r < 16; ++r) s_prev[kt][r] += tmp[kt][r];
                }
                WAIT_VM0();                                  // DMA(i+2) landed before barrier
            }
            BARRIER_LDS();                                   // barriers #3..#67
        }
        // epilogue: row-sum handoff
        float tot = lacc + __shfl_xor(lacc, 32);
        if (hi == 0) lsumF[w * 32 + l31] = tot;
        BARRIER_LDS();                                       // barrier #68
    } else {
        // ==================== CONSUMER region (waves 4-11, 2/SIMD) ====================
        const int ci = w - 4;                                // 0..7: 32 c-rows at ci*32
        v16f o[4];                                           // acc [qt], 64 regs
#pragma unroll
        for (int qt = 0; qt < 4; ++qt)
#pragma unroll
            for (int r = 0; r < 16; ++r) o[qt][r] = 0.f;
        const unsigned short* vb0 = Vb + (size_t)(ci * 32 + l31) * NHW + hi * 8;
        v8bf av[4];                                          // V frags of next PV tile
#pragma unroll
        for (int kf = 0; kf < 4; ++kf)
            av[kf] = *(const v8bf*)(vb0 + kf * 16);
        BARRIER_LDS();                                       // barrier #1
        BARRIER_LDS();                                       // barrier #2 (P prologue B window)

        for (int it = 0; it < 65; ++it) {
            if (it > 0) {
                // PV over tile it-1 from Pu[(it-1)&1]; kf-major, 4 acc chains
                const int pbuf = (it - 1) & 1;
                const unsigned short* pb = PuS + pbuf * 8192 + (hi * 32 + l31) * 8;
#pragma unroll
                for (int kf = 0; kf < 4; ++kf) {
                    v8bf bp[4];
#pragma unroll
                    for (int qt = 0; qt < 4; ++qt)
                        bp[qt] = *(const v8bf*)(pb + (qt * 4 + kf) * 512);
#pragma unroll
                    for (int qt = 0; qt < 4; ++qt)
                        o[qt] = __builtin_amdgcn_mfma_f32_32x32x16_bf16(av[kf], bp[qt], o[qt], 0, 0, 0);
                }
                // reload V frags for tile it (wrapped at it=64: dead uniform load)
                const size_t kc0 = (size_t)(it & 63) * 64;
#pragma unroll
                for (int kf = 0; kf < 4; ++kf)
                    av[kf] = *(const v8bf*)(vb0 + kc0 + kf * 16);
            }
            BARRIER_LDS();                                   // barriers #3..#67
        }
        BARRIER_LDS();                                       // barrier #68 (lsum ready)
        float inv[4];
#pragma unroll
        for (int qt = 0; qt < 4; ++qt) inv[qt] = 1.0f / lsumF[qt * 32 + l31];
        // store: O^T C/D lane = q-col -> coalesced dwords
#pragma unroll
        for (int qt = 0; qt < 4; ++qt) {
            float* ob = out + (size_t)b * NC * NHW + q128 + qt * 32 + l31;
#pragma unroll
            for (int r = 0; r < 16; ++r) {
                int c = ci * 32 + (r & 3) + 8 * (r >> 2) + 4 * hi;
                ob[(size_t)c * NHW] = o[qt][r] * inv[qt];
            }
        }
    }
}

extern "C" void kernel_launch(void* const* d_in, const int* in_sizes, int n_in,
                              void* d_out, int out_size, void* d_ws, size_t ws_size,
                              hipStream_t stream) {
    const float* l  = (const float*)d_in[0];
    const float* wt = (const float*)d_in[1];
    const float* wp = (const float*)d_in[2];
    float* out = (float*)d_out;

    char* ws = (char*)d_ws;
    unsigned short* Wbf = (unsigned short*)ws;                          // 131072 B
    unsigned short* Qbf = (unsigned short*)(ws + 131072);               // 8 MB
    unsigned short* Kbf = (unsigned short*)(ws + 131072 + 8388608);     // 8 MB (pre-swizzled)
    unsigned short* Vbf = (unsigned short*)(ws + 131072 + 16777216);    // 16 MB (linear)

    hipLaunchKernelGGL(cast_w_kernel, dim3(256), dim3(256), 0, stream, wt, wp, Wbf);
    hipLaunchKernelGGL(proj_kernel,   dim3(512), dim3(256), 0, stream, l, Wbf, Qbf, Kbf, Vbf);
    // q-tile 128: 8 batches x 32 q-tiles = 256 blocks of 768 threads (12 waves)
    hipLaunchKernelGGL(attn_kernel,   dim3(256), dim3(768), 0, stream, Qbf, Kbf, Vbf, out);
}

// Round 17
// 196.159 us; speedup vs baseline: 1.0668x; 1.0322x over previous
//
#include <hip/hip_runtime.h>
#include <stdint.h>

#define NB 8
#define NC 256
#define NE 128
#define NHW 4096

typedef __bf16 v8bf __attribute__((ext_vector_type(8)));
typedef float v4f __attribute__((ext_vector_type(4)));
typedef float v16f __attribute__((ext_vector_type(16)));
typedef unsigned int v4u __attribute__((ext_vector_type(4)));
typedef unsigned int v2u __attribute__((ext_vector_type(2)));

typedef unsigned int __attribute__((address_space(1))) uint_g;
typedef unsigned int __attribute__((address_space(3))) uint_l;

#if __has_builtin(__builtin_amdgcn_exp2f)
#define EXP2F(x) __builtin_amdgcn_exp2f(x)
#else
#define EXP2F(x) exp2f(x)
#endif

// LDS-only barrier: drains lgkmcnt but NOT vmcnt (global prefetch/DMA stays in flight)
#define BARRIER_LDS() asm volatile("s_waitcnt lgkmcnt(0)\n\ts_barrier" ::: "memory")
#define WAIT_VM0()    asm volatile("s_waitcnt vmcnt(0)" ::: "memory")

// async global->LDS DMA, 16B per lane: LDS dst = uniform base + lane*16
__device__ __forceinline__ void dma16(const unsigned short* g, unsigned short* l) {
    __builtin_amdgcn_global_load_lds((const uint_g*)g, (uint_l*)l, 16, 0, 0);
}

// fp32 -> bf16 round-to-nearest-even
__device__ __forceinline__ unsigned short f2bf(float x) {
    union { float f; unsigned int u; } v; v.f = x;
    unsigned int r = v.u + 0x7fffu + ((v.u >> 16) & 1u);
    return (unsigned short)(r >> 16);
}

// pack two fp32 -> bf16x2, round-half-up (P in (0,1], R4-verified accuracy)
__device__ __forceinline__ unsigned int pack_bf2_ru(float a, float b) {
    union { float f; unsigned int u; } va, vb; va.f = a; vb.f = b;
    return ((va.u + 0x8000u) >> 16) | ((vb.u + 0x8000u) & 0xffff0000u);
}

// ---------------- K0: cast weights. Wbf[e][c], e<128 = w_theta*(scale*log2e), e>=128 = w_phi
__global__ __launch_bounds__(256) void cast_w_kernel(const float* __restrict__ wt,
                                                     const float* __restrict__ wp,
                                                     unsigned short* __restrict__ Wbf) {
    int i = blockIdx.x * 256 + threadIdx.x;
    const float QS = 0.08838834764831845f * 1.4426950408889634f;
    float v = (i < 32768) ? wt[i] * QS : wp[i - 32768];
    Wbf[i] = f2bf(v);
}

// ---------------- K1: projection (+ fused V cast). K is stored PRE-SWIZZLED
// (16B unit u at position u ^ (row&15) within each row) so attn's LDS DMA copy
// is read conflict-free with the R5-verified fragment pattern. Q unswizzled.
// R0-exact form: 64-hw tile (R6's 32-tile regressed: W re-read doubling);
// linear V (R12's tiled V was attn-null and cost ~3us here).
__global__ __launch_bounds__(256, 2) void proj_kernel(const float* __restrict__ l,
                                                      const unsigned short* __restrict__ Wbf,
                                                      unsigned short* __restrict__ Qbf,
                                                      unsigned short* __restrict__ Kbf,
                                                      unsigned short* __restrict__ Vbf) {
    __shared__ __align__(16) unsigned short A[64][264];
    __shared__ __align__(16) unsigned short Ost[2][32][136];
    const int tid = threadIdx.x;
    const int b = blockIdx.x & 7;
    const int qt = (blockIdx.x >> 3) << 6;
    const float* lb = l + ((size_t)b * NC * NHW + qt);

    for (int s = 0; s < 16; ++s) {
        int f = tid + s * 256;
        int c = f >> 4, j = f & 15;
        float4 v = *(const float4*)(lb + (size_t)c * NHW + j * 4);
        ushort4 o4;
        o4.x = f2bf(v.x); o4.y = f2bf(v.y); o4.z = f2bf(v.z); o4.w = f2bf(v.w);
        A[j * 4 + 0][c] = o4.x;
        A[j * 4 + 1][c] = o4.y;
        A[j * 4 + 2][c] = o4.z;
        A[j * 4 + 3][c] = o4.w;
        *(ushort4*)(Vbf + (size_t)b * NC * NHW + (size_t)c * NHW + qt + j * 4) = o4;
    }
    __syncthreads();

    const int w = tid >> 6, L = tid & 63;
    const int l15 = L & 15, q4 = L >> 4;
    const v4f vz = {0.f, 0.f, 0.f, 0.f};
    v4f acc[4][4];
    for (int mt = 0; mt < 4; ++mt)
        for (int nt = 0; nt < 4; ++nt) acc[mt][nt] = vz;

    for (int kf = 0; kf < 8; ++kf) {
        int kc = kf * 32 + q4 * 8;
        v8bf a[4], bb[4];
        for (int mt = 0; mt < 4; ++mt)
            a[mt] = *(const v8bf*)&A[mt * 16 + l15][kc];
        for (int nt = 0; nt < 4; ++nt)
            bb[nt] = *(const v8bf*)(Wbf + (w * 64 + nt * 16 + l15) * 256 + kc);
        for (int mt = 0; mt < 4; ++mt)
            for (int nt = 0; nt < 4; ++nt)
                acc[mt][nt] = __builtin_amdgcn_mfma_f32_16x16x32_bf16(a[mt], bb[nt], acc[mt][nt], 0, 0, 0);
    }

    const int side = w >> 1;
    const int ebase = (w & 1) * 64;
#pragma unroll
    for (int ph = 0; ph < 2; ++ph) {
        __syncthreads();
#pragma unroll
        for (int mh = 0; mh < 2; ++mh) {
            int mt = ph * 2 + mh;
#pragma unroll
            for (int nt = 0; nt < 4; ++nt)
#pragma unroll
                for (int r = 0; r < 4; ++r) {
                    int q32 = mh * 16 + q4 * 4 + r;
                    Ost[side][q32][ebase + nt * 16 + l15] = f2bf(acc[mt][nt][r]);
                }
        }
        __syncthreads();
#pragma unroll
        for (int s = 0; s < 4; ++s) {
            int idx = tid + s * 256;
            int sd = idx >> 9, rem = idx & 511;
            int r32 = rem >> 4, c8 = rem & 15;
            unsigned short* dst = sd ? Kbf : Qbf;
            int c8s = sd ? (c8 ^ (r32 & 15)) : c8;   // pre-swizzle K only
            *(uint4*)(dst + ((size_t)b * NHW + qt + ph * 32 + r32) * NE + c8s * 8) =
                *(const uint4*)&Ost[sd][r32][c8 * 8];
        }
    }
}

// ---------------- K2: flash attention, SPLIT-LOOP producer/consumer wave
// specialization (R8 structure) + R9 direct-scatter + R10 k-tile 128 + R11
// accumulator interleave.  R17 = CONSOLIDATION on the best-measured build
// (R11, 194.2us total / 109.6us attn).
// Session ledger (what is known about this structure):
//  - 2 waves/SIMD, P/C-paired, full 256-reg budget is OPTIMAL.  Measured
//    alternatives: 4 waves @128 regs = spill (R1); single-loop pipelining =
//    spill (R3/R5); homogeneous waves = no overlap (R4); setprio = -8% (R7);
//    2 same-role waves/SIMD = +18% time (R15); 3 waves/SIMD @170 regs = +24%
//    time (R16); 2 blocks/CU TLP = no help (R15).
//  - Split-loop P/C regions decouple liveness (R8: VGPR 128->96, -10us).
//  - Direct-scatter P^T (R9: -15.5us), k-tile 128 (R10: -5us round overhead),
//    8-chain MFMA interleave (R11: null but harmless), V-load coalescing
//    (R12: null -> VMEM not binding).
//  - Remaining ~55% matrix-idle/round is intra-round latency coupling not
//    resolvable with available counters; 6 structural probes all null/worse.
// Schedule: P iter i = DMA K(i+2) || softmax(i) from s_prev -> scatter ||
// QK(i+1) -> s_prev.  Parity: P writes Pu[it&1], C reads Pu[(it-1)&1];
// QK(i+1) reads Ku[(i+1)&1], DMA(i+2) fills Ku[i&1].  Barriers 36/36.
// LDS: Ku dbuf 64K | Pu dbuf 64K | lsum 512B = 131584 B (1 block/CU).
__global__ __launch_bounds__(512, 2) void attn_kernel(const unsigned short* __restrict__ Qbf,
                                                      const unsigned short* __restrict__ Kbf,
                                                      const unsigned short* __restrict__ Vbf,
                                                      float* __restrict__ out) {
    __shared__ __align__(16) unsigned char smem[131584];
    unsigned short* KuS = (unsigned short*)smem;             // 2 x 32KB, swizzled tiles
    unsigned short* PuS = (unsigned short*)(smem + 65536);   // 2 x 32 frag-tiles x 1KB
    float* lsumF = (float*)(smem + 131072);                  // [4][32]

    const int tid = threadIdx.x;
    const int b = blockIdx.x & 7;                            // batch -> XCD affinity
    const int q128 = (blockIdx.x >> 3) << 7;
    const int w = tid >> 6;                                  // wave 0-7 -> SIMD w&3
    const int L = tid & 63;
    const int l31 = L & 31, hi = L >> 5;
    const int x15 = l31 & 15;

    const unsigned short* Kb = Kbf + (size_t)b * NHW * NE;
    const unsigned short* Vb = Vbf + (size_t)b * NC * NHW;

    if (w < 4) {
        // ==================== PRODUCER region ====================
        float lacc = 0.f;
        v8bf bq[8];
        const unsigned short* qrow = Qbf + ((size_t)b * NHW + q128 + w * 32 + l31) * NE + hi * 8;
#pragma unroll
        for (int ef = 0; ef < 8; ++ef)
            bq[ef] = *(const v8bf*)(qrow + ef * 16);
        // prologue A: DMA K tile 0 (128 rows = 32 chunks, 8/wave) -> buf 0
#pragma unroll
        for (int jj = 0; jj < 8; ++jj) {
            int j = w * 8 + jj;
            dma16(Kb + (size_t)j * 512 + L * 8, KuS + j * 512);
        }
        WAIT_VM0();
        BARRIER_LDS();                                       // barrier #1
        // prologue B: DMA K tile 1 -> buf 1; QK(0) -> s_prev (8-chain interleave)
#pragma unroll
        for (int jj = 0; jj < 8; ++jj) {
            int j = w * 8 + jj;
            dma16(Kb + (size_t)16384 + j * 512 + L * 8, KuS + 16384 + j * 512);
        }
        v16f s_prev[4];
        {
            v16f tmp[4];
#pragma unroll
            for (int kt = 0; kt < 4; ++kt)
#pragma unroll
                for (int r = 0; r < 16; ++r) { s_prev[kt][r] = 0.f; tmp[kt][r] = 0.f; }
#pragma unroll
            for (int ef = 0; ef < 4; ++ef)
#pragma unroll
                for (int kt = 0; kt < 4; ++kt) {
                    const unsigned short* krow = KuS + (kt * 32 + l31) * 128;
                    v8bf ak0 = *(const v8bf*)(krow + (((2 * ef + hi) ^ x15) * 8));
                    v8bf ak1 = *(const v8bf*)(krow + (((2 * (ef + 4) + hi) ^ x15) * 8));
                    s_prev[kt] = __builtin_amdgcn_mfma_f32_32x32x16_bf16(ak0, bq[ef], s_prev[kt], 0, 0, 0);
                    tmp[kt]    = __builtin_amdgcn_mfma_f32_32x32x16_bf16(ak1, bq[ef + 4], tmp[kt], 0, 0, 0);
                }
#pragma unroll
            for (int kt = 0; kt < 4; ++kt)
#pragma unroll
                for (int r = 0; r < 16; ++r) s_prev[kt][r] += tmp[kt][r];
        }
        WAIT_VM0();                                          // DMA(1) landed
        BARRIER_LDS();                                       // barrier #2

        // scatter-write address components (loop-invariant; R9-verified image)
        const int a1 = l31 * 8 + hi * 4;                     // shorts: unit l31, word-half hi
        const int a2 = (l31 + 32) * 8 + hi * 4;              // shorts: unit l31+32, word-half hi

        for (int it = 0; it < 33; ++it) {
            if (it < 32) {
                const int buf = it & 1;                      // Pu publish buf; DMA(i+2) Ku buf
                if (it <= 29) {
                    // DMA K(i+2) into Ku buf[(i+2)&1] = buf[i&1] (tile i dead: QK'd last iter)
                    const size_t kro = (size_t)(it + 2) * 16384;   // shorts: tile*128rows*128
#pragma unroll
                    for (int jj = 0; jj < 8; ++jj) {
                        int j = w * 8 + jj;
                        dma16(Kb + kro + j * 512 + L * 8, KuS + buf * 16384 + j * 512);
                    }
                }
                // softmax(i) from s_prev -> scatter into Pu[buf]
#pragma unroll
                for (int kt = 0; kt < 4; ++kt) {
                    float p[16];
#pragma unroll
                    for (int r = 0; r < 16; ++r) p[r] = EXP2F(s_prev[kt][r]);
                    {   // row-sum: depth-4 tree (R9-verified)
                        float t0 = (p[0] + p[1]) + (p[2] + p[3]);
                        float t1 = (p[4] + p[5]) + (p[6] + p[7]);
                        float t2 = (p[8] + p[9]) + (p[10] + p[11]);
                        float t3 = (p[12] + p[13]) + (p[14] + p[15]);
                        lacc += (t0 + t1) + (t2 + t3);
                    }
                    unsigned int pk[8];
#pragma unroll
                    for (int t = 0; t < 8; ++t) pk[t] = pack_bf2_ru(p[2 * t], p[2 * t + 1]);
                    unsigned short* base0 = PuS + buf * 16384 + (w * 8 + kt * 2) * 512;
                    *(v2u*)(base0 + a1)       = (v2u){pk[0], pk[1]};
                    *(v2u*)(base0 + a2)       = (v2u){pk[2], pk[3]};
                    *(v2u*)(base0 + 512 + a1) = (v2u){pk[4], pk[5]};
                    *(v2u*)(base0 + 512 + a2) = (v2u){pk[6], pk[7]};
                }
                // QK(i+1) -> s_prev (direct accumulate; 8 chains in flight)
                if (it <= 30) {
                    const unsigned short* kub = KuS + ((it + 1) & 1) * 16384;
                    v16f tmp[4];
#pragma unroll
                    for (int kt = 0; kt < 4; ++kt)
#pragma unroll
                        for (int r = 0; r < 16; ++r) { s_prev[kt][r] = 0.f; tmp[kt][r] = 0.f; }
#pragma unroll
                    for (int ef = 0; ef < 4; ++ef)
#pragma unroll
                        for (int kt = 0; kt < 4; ++kt) {
                            const unsigned short* krow = kub + (kt * 32 + l31) * 128;
                            v8bf ak0 = *(const v8bf*)(krow + (((2 * ef + hi) ^ x15) * 8));
                            v8bf ak1 = *(const v8bf*)(krow + (((2 * (ef + 4) + hi) ^ x15) * 8));
                            s_prev[kt] = __builtin_amdgcn_mfma_f32_32x32x16_bf16(ak0, bq[ef], s_prev[kt], 0, 0, 0);
                            tmp[kt]    = __builtin_amdgcn_mfma_f32_32x32x16_bf16(ak1, bq[ef + 4], tmp[kt], 0, 0, 0);
                        }
#pragma unroll
                    for (int kt = 0; kt < 4; ++kt)
#pragma unroll
                        for (int r = 0; r < 16; ++r) s_prev[kt][r] += tmp[kt][r];
                }
                WAIT_VM0();                                  // DMA(i+2) landed before barrier
            }
            BARRIER_LDS();                                   // barriers #3..#35
        }
        // epilogue: row-sum handoff
        float tot = lacc + __shfl_xor(lacc, 32);
        if (hi == 0) lsumF[w * 32 + l31] = tot;
        BARRIER_LDS();                                       // barrier #36
    } else {
        // ==================== CONSUMER region ====================
        const int ci = w - 4;
        v16f o[2][4];                                        // acc [ct][qt], 128 regs
#pragma unroll
        for (int ct = 0; ct < 2; ++ct)
#pragma unroll
            for (int qt = 0; qt < 4; ++qt)
#pragma unroll
                for (int r = 0; r < 16; ++r) o[ct][qt][r] = 0.f;
        const unsigned short* vb0 = Vb + (size_t)(ci * 64 + l31) * NHW + hi * 8;
        const unsigned short* vb1 = Vb + (size_t)(ci * 64 + 32 + l31) * NHW + hi * 8;
        v8bf av[2][4];                                       // kf0-3 of next PV tile
#pragma unroll
        for (int kf = 0; kf < 4; ++kf) {
            av[0][kf] = *(const v8bf*)(vb0 + kf * 16);
            av[1][kf] = *(const v8bf*)(vb1 + kf * 16);
        }
        BARRIER_LDS();                                       // barrier #1
        BARRIER_LDS();                                       // barrier #2 (P prologue B window)

        for (int it = 0; it < 33; ++it) {
            if (it > 0) {
                // issue kf4-7 V frags of tile it-1 early (landed under first-half MFMAs)
                const size_t kcA = (size_t)(it - 1) * 128;
                v8bf av2[2][4];
#pragma unroll
                for (int kf = 0; kf < 4; ++kf) {
                    av2[0][kf] = *(const v8bf*)(vb0 + kcA + (kf + 4) * 16);
                    av2[1][kf] = *(const v8bf*)(vb1 + kcA + (kf + 4) * 16);
                }
                const int pbuf = (it - 1) & 1;
                const unsigned short* pb = PuS + pbuf * 16384 + (hi * 32 + l31) * 8;
                // kf-major: per kf, 4 bp reads then 8 MFMAs across all 8 accumulators
#pragma unroll
                for (int kf = 0; kf < 4; ++kf) {
                    v8bf bp[4];
#pragma unroll
                    for (int qt = 0; qt < 4; ++qt)
                        bp[qt] = *(const v8bf*)(pb + (qt * 8 + kf) * 512);
#pragma unroll
                    for (int qt = 0; qt < 4; ++qt) {
                        o[0][qt] = __builtin_amdgcn_mfma_f32_32x32x16_bf16(av[0][kf], bp[qt], o[0][qt], 0, 0, 0);
                        o[1][qt] = __builtin_amdgcn_mfma_f32_32x32x16_bf16(av[1][kf], bp[qt], o[1][qt], 0, 0, 0);
                    }
                }
#pragma unroll
                for (int kf = 0; kf < 4; ++kf) {
                    v8bf bp[4];
#pragma unroll
                    for (int qt = 0; qt < 4; ++qt)
                        bp[qt] = *(const v8bf*)(pb + (qt * 8 + 4 + kf) * 512);
#pragma unroll
                    for (int qt = 0; qt < 4; ++qt) {
                        o[0][qt] = __builtin_amdgcn_mfma_f32_32x32x16_bf16(av2[0][kf], bp[qt], o[0][qt], 0, 0, 0);
                        o[1][qt] = __builtin_amdgcn_mfma_f32_32x32x16_bf16(av2[1][kf], bp[qt], o[1][qt], 0, 0, 0);
                    }
                }
                // preload kf0-3 of tile it (wrapped at it=32: dead uniform load)
                const size_t kcB = (size_t)(it & 31) * 128;
#pragma unroll
                for (int kf = 0; kf < 4; ++kf) {
                    av[0][kf] = *(const v8bf*)(vb0 + kcB + kf * 16);
                    av[1][kf] = *(const v8bf*)(vb1 + kcB + kf * 16);
                }
            }
            BARRIER_LDS();                                   // barriers #3..#35
        }
        BARRIER_LDS();                                       // barrier #36 (lsum ready)
        float inv[4];
#pragma unroll
        for (int qt = 0; qt < 4; ++qt) inv[qt] = 1.0f / lsumF[qt * 32 + l31];
        // store: O^T C/D lane = q-col -> coalesced dwords
#pragma unroll
        for (int ct = 0; ct < 2; ++ct)
#pragma unroll
            for (int qt = 0; qt < 4; ++qt) {
                float* ob = out + (size_t)b * NC * NHW + q128 + qt * 32 + l31;
#pragma unroll
                for (int r = 0; r < 16; ++r) {
                    int c = ci * 64 + ct * 32 + (r & 3) + 8 * (r >> 2) + 4 * hi;
                    ob[(size_t)c * NHW] = o[ct][qt][r] * inv[qt];
                }
            }
    }
}

extern "C" void kernel_launch(void* const* d_in, const int* in_sizes, int n_in,
                              void* d_out, int out_size, void* d_ws, size_t ws_size,
                              hipStream_t stream) {
    const float* l  = (const float*)d_in[0];
    const float* wt = (const float*)d_in[1];
    const float* wp = (const float*)d_in[2];
    float* out = (float*)d_out;

    char* ws = (char*)d_ws;
    unsigned short* Wbf = (unsigned short*)ws;                          // 131072 B
    unsigned short* Qbf = (unsigned short*)(ws + 131072);               // 8 MB
    unsigned short* Kbf = (unsigned short*)(ws + 131072 + 8388608);     // 8 MB (pre-swizzled)
    unsigned short* Vbf = (unsigned short*)(ws + 131072 + 16777216);    // 16 MB (linear)

    hipLaunchKernelGGL(cast_w_kernel, dim3(256), dim3(256), 0, stream, wt, wp, Wbf);
    hipLaunchKernelGGL(proj_kernel,   dim3(512), dim3(256), 0, stream, l, Wbf, Qbf, Kbf, Vbf);
    // q-tile 128: 8 batches x 32 q-tiles = 256 blocks of 512 threads (8 waves)
    hipLaunchKernelGGL(attn_kernel,   dim3(256), dim3(512), 0, stream, Qbf, Kbf, Vbf, out);
}